// Round 10
// baseline (2231.030 us; speedup 1.0000x reference)
//
#include <hip/hip_runtime.h>

// Sizes (fixed): V=512, F_IN=8, H=64, DH=4, T=3, E=8192, P=64, L=8, D=68

__device__ __forceinline__ float fsig_(float x) { return 1.f / (1.f + __expf(-x)); }
__device__ __forceinline__ float ftanh_(float x) {
  float e = __expf(2.f * x);
  return 1.f - 2.f / (e + 1.f);
}
__device__ __forceinline__ float sig_(float x) { return 1.f / (1.f + expf(-x)); }

// Barrier WITHOUT vmcnt drain: LDS ordering only.
__device__ __forceinline__ void barrier_lgkm() {
  asm volatile("s_waitcnt lgkmcnt(0)\n\ts_barrier" ::: "memory");
}

// Pin a float4 into VGPRs (opaque redefinition, blocks rematerialization).
#define PIN4(v) asm volatile("" : "+v"((v).x), "+v"((v).y), "+v"((v).z), "+v"((v).w))

// NOTE: macro params must NOT collide with float4 member names (x/y/z/w).
#define LD4(p) (*(const float4*)(p))
#define DOT4(acc, va, vb)                                                      \
  do {                                                                         \
    acc += (va).x * (vb).x; acc += (va).y * (vb).y;                            \
    acc += (va).z * (vb).z; acc += (va).w * (vb).w;                            \
  } while (0)

#define ALL16(M) M(0) M(1) M(2) M(3) M(4) M(5) M(6) M(7)                       \
                 M(8) M(9) M(10) M(11) M(12) M(13) M(14) M(15)
#define ALLQ(M) M(0,0) M(1,1) M(2,2) M(3,3) M(4,0) M(5,1) M(6,2) M(7,3)        \
                M(8,0) M(9,1) M(10,2) M(11,3) M(12,0) M(13,1) M(14,2) M(15,3)
#define ALL8(M) M(0) M(1) M(2) M(3) M(4) M(5) M(6) M(7)
#define ALLQ8(M) M(0,0) M(1,1) M(2,2) M(3,3) M(4,0) M(5,1) M(6,2) M(7,3)

// x[i,j,h] = sum_f adj[i,j,f] * emb[h,f]
__global__ __launch_bounds__(256) void embed_kernel(
    const float* __restrict__ adj, const float* __restrict__ emb,
    float* __restrict__ x)
{
  const int64_t row = (int64_t)blockIdx.x * 4 + (threadIdx.x >> 6);
  const int h = threadIdx.x & 63;
  const float* a = adj + row * 8;
  float acc = 0.f;
#pragma unroll
  for (int f = 0; f < 8; ++f) acc += a[f] * emb[h * 8 + f];
  x[row * 64 + h] = acc;
}

// col_sum[j,h] = sum_i x[i,j,h];  col_nz[j] = sum_i sum_h (x[i,j,h]!=0)
__global__ __launch_bounds__(256) void colsum_kernel(
    const float* __restrict__ x, float* __restrict__ col_sum,
    int* __restrict__ col_nz)
{
  const int j = blockIdx.x;
  const int h = threadIdx.x & 63;
  const int w = threadIdx.x >> 6;
  float acc = 0.f;
  int nz = 0;
  for (int i = w; i < 512; i += 4) {
    float v = x[((int64_t)i * 512 + j) * 64 + h];
    acc += v;
    nz += (v != 0.f) ? 1 : 0;
  }
  __shared__ float pacc[4][64];
  __shared__ int pnz[4];
#pragma unroll
  for (int off = 32; off > 0; off >>= 1) nz += __shfl_down(nz, off, 64);
  if (h == 0) pnz[w] = nz;
  pacc[w][h] = acc;
  __syncthreads();
  if (w == 0) {
    col_sum[j * 64 + h] = pacc[0][h] + pacc[1][h] + pacc[2][h] + pacc[3][h];
    if (h == 0) col_nz[j] = pnz[0] + pnz[1] + pnz[2] + pnz[3];
  }
}

__global__ void scatter_idx_kernel(const int* __restrict__ edges,
                                   int* __restrict__ idxmap)
{
  const int e = blockIdx.x * 256 + threadIdx.x;
  if (e < 8192) idxmap[edges[e * 2] * 512 + edges[e * 2 + 1]] = e;
}

// Per-edge message m_e, then delta_gi[e,g] = sum_h (m_e[h]-x_uv[h]) * w_ih[g,h]
__global__ __launch_bounds__(64) void edge_kernel(
    const float* __restrict__ x, const int* __restrict__ edges,
    const float* __restrict__ col_sum, const int* __restrict__ col_nz,
    const float* __restrict__ w1, const float* __restrict__ w2,
    const float* __restrict__ w3, const float* __restrict__ w_ih,
    float* __restrict__ delta_gi)
{
  const int e = blockIdx.x;
  const int h = threadIdx.x;
  const int u = edges[e * 2 + 0];
  const int v = edges[e * 2 + 1];
  __shared__ __align__(16) float xuv[64], ein[64], eout[64], dm[64];
  const float xuvh = x[((int64_t)u * 512 + v) * 64 + h];
  const float xvuh = x[((int64_t)v * 512 + u) * 64 + h];
  xuv[h] = xuvh;
  const int nz_vu = __popcll(__ballot(xvuh != 0.f));
  const int nz_uv = __popcll(__ballot(xuvh != 0.f));
  float n_in = (float)(col_nz[u] - nz_vu) / 64.f;
  if (n_in == 0.f) n_in = 1.f;
  float n_out = (float)(col_nz[v] - nz_uv) / 64.f;
  if (n_out == 0.f) n_out = 1.f;
  ein[h] = (col_sum[u * 64 + h] - xvuh) / n_in;
  eout[h] = (col_sum[v * 64 + h] - xuvh) / n_out;
  __syncthreads();
  const float4* w1r = (const float4*)(w1 + h * 64);
  const float4* w2r = (const float4*)(w2 + h * 64);
  const float4* w3r = (const float4*)(w3 + h * 64);
  const float4* xuv4 = (const float4*)xuv;
  const float4* ein4 = (const float4*)ein;
  const float4* eout4 = (const float4*)eout;
  float acc = 0.f;
#pragma unroll
  for (int kk = 0; kk < 16; ++kk) {
    float4 a = xuv4[kk], b = w1r[kk];
    acc += a.x * b.x + a.y * b.y + a.z * b.z + a.w * b.w;
    a = ein4[kk]; b = w2r[kk];
    acc += a.x * b.x + a.y * b.y + a.z * b.z + a.w * b.w;
    a = eout4[kk]; b = w3r[kk];
    acc += a.x * b.x + a.y * b.y + a.z * b.z + a.w * b.w;
  }
  const float m = fmaxf(acc, 0.f);
  dm[h] = m - xuvh;
  __syncthreads();
  const float4* dm4 = (const float4*)dm;
#pragma unroll
  for (int r = 0; r < 3; ++r) {
    const int gg = h + r * 64;
    const float4* wr = (const float4*)(w_ih + gg * 128);
    float d = 0.f;
#pragma unroll
    for (int kk = 0; kk < 16; ++kk) {
      float4 a = dm4[kk], b = wr[kk];
      d += a.x * b.x + a.y * b.y + a.z * b.z + a.w * b.w;
    }
    delta_gi[e * 192 + gg] = d;
  }
}

// ---- GRU scan v6: low-register decomposition, everything resident. ----
// 768 thr = 12 waves = TWO rows, grid 256 = all 512 rows in ONE pass.
// Waves 6-11 (producers, serve BOTH rows): wave -> (gate-group gg, K-half).
//   W = 8 f4 (32 VGPR, K-half of wsum); X prefetch 8 f4 per row.
//   Writes K-half partial of gi[t+1] to gpart LDS. ~110 VGPR.
// Waves 0-5 (consumers, 3 per row: r/z/n): 16 f4 weights (64 VGPR) each.
//   r,z published to LDS before B1; n-wave completes h after B1. ~85 VGPR.
// Every branch fits 128 VGPR -> no AGPR spilling possible.
#define DECL_WP(i)                                                             \
  float4 WP##i; {                                                              \
    float4 t0 = LD4(wg + 4 * (i));                                             \
    float4 t1 = LD4(wg2 + 4 * (i));                                            \
    WP##i.x = t0.x + t1.x; WP##i.y = t0.y + t1.y;                              \
    WP##i.z = t0.z + t1.z; WP##i.w = t0.w + t1.w;                              \
  }                                                                            \
  PIN4(WP##i);
#define DECL_XA(i) float4 XA##i = LD4(xpA + 4 * (i));
#define DECL_XB(i) float4 XB##i = LD4(xpB + 4 * (i));
#define PQA(i, q) { DOT4(ac##q, XA##i, WP##i); XA##i = LD4(xnext + 4 * (i)); }
#define PQB(i, q) { DOT4(ac##q, XB##i, WP##i); XB##i = LD4(xnext + 4 * (i)); }
#define DECL_WC(i) float4 WC##i = LD4(wc + 4 * (i)); PIN4(WC##i);
#define CCH(i, q) { float4 hc = hs4[(i)]; DOT4(a##q, hc, WC##i); }

__global__ __launch_bounds__(768, 3) void scan_kernel(
    float* __restrict__ x, const float* __restrict__ delta_gi,
    const int* __restrict__ idxmap,
    const float* __restrict__ w_ih, const float* __restrict__ w_hh,
    const float* __restrict__ b_ih, const float* __restrict__ b_hh)
{
  const int tid = threadIdx.x;
  const int wave = tid >> 6;
  const int lane = tid & 63;
  const int64_t b0 = (int64_t)blockIdx.x * 2;

  __shared__ float gpart[2][2][2][192];  // [row][buf][khalf][gate]
  __shared__ __align__(16) float hs[2][64];
  __shared__ float rbuf[2][64], zbuf[2][64];
  __shared__ int idxl[2][512];

  for (int i = tid; i < 1024; i += 768) {
    const int r_ = i >> 9, ii = i & 511;
    idxl[r_][ii] = idxmap[(b0 + r_) * 512 + ii];
  }
  if (tid < 128) hs[tid >> 6][tid & 63] = 0.f;
  __syncthreads();

  if (wave >= 6) {
    // ---------------- producer (both rows) ----------------
    const int pidx = wave - 6;
    const int gg = pidx >> 1, khalf = pidx & 1;
    const int g = gg * 64 + lane;
    const float* wg = w_ih + g * 128 + khalf * 32;
    const float* wg2 = wg + 64;
    ALL8(DECL_WP)
    const float bi = khalf ? 0.f : b_ih[g];
    float* xrowA = x + b0 * 32768;
    float* xrowB = xrowA + 32768;
    const float* xpA = xrowA + khalf * 32;
    const float* xpB = xrowB + khalf * 32;
    ALL8(DECL_XA)   // XA = x_rowA[0] half
    ALL8(DECL_XB)   // XB = x_rowB[0] half
    {  // prologue: gi[0] partials, row A (reload XA <- x[1])
      const float* xnext = xrowA + 64 + khalf * 32;
      float ac0 = bi, ac1 = 0.f, ac2 = 0.f, ac3 = 0.f;
      ALLQ8(PQA)
      float acc = (ac0 + ac1) + (ac2 + ac3);
      if (!khalf) {
        const int i0 = idxl[0][0];
        if (i0 >= 0) acc += delta_gi[(int64_t)i0 * 192 + g];
      }
      gpart[0][0][khalf][g] = acc;
    }
    {  // prologue row B
      const float* xnext = xrowB + 64 + khalf * 32;
      float ac0 = bi, ac1 = 0.f, ac2 = 0.f, ac3 = 0.f;
      ALLQ8(PQB)
      float acc = (ac0 + ac1) + (ac2 + ac3);
      if (!khalf) {
        const int i0 = idxl[1][0];
        if (i0 >= 0) acc += delta_gi[(int64_t)i0 * 192 + g];
      }
      gpart[1][0][khalf][g] = acc;
    }
    float dgnA = 0.f, dgnB = 0.f;
    if (!khalf) {
      const int iA = idxl[0][1];
      if (iA >= 0) dgnA = delta_gi[(int64_t)iA * 192 + g];
      const int iB = idxl[1][1];
      if (iB >= 0) dgnB = delta_gi[(int64_t)iB * 192 + g];
    }
    barrier_lgkm();  // B0: gi[0] published
    for (int t = 0; t < 512; ++t) {
      if (t < 511) {
        const int tn2 = (t + 2 < 512) ? t + 2 : 511;
        {
          const float* xnext = xrowA + tn2 * 64 + khalf * 32;
          float ac0 = bi + dgnA, ac1 = 0.f, ac2 = 0.f, ac3 = 0.f;
          ALLQ8(PQA)
          gpart[0][(t + 1) & 1][khalf][g] = (ac0 + ac1) + (ac2 + ac3);
        }
        {
          const float* xnext = xrowB + tn2 * 64 + khalf * 32;
          float ac0 = bi + dgnB, ac1 = 0.f, ac2 = 0.f, ac3 = 0.f;
          ALLQ8(PQB)
          gpart[1][(t + 1) & 1][khalf][g] = (ac0 + ac1) + (ac2 + ac3);
        }
        if (!khalf) {
          const int iA = idxl[0][tn2];
          dgnA = (iA >= 0) ? delta_gi[(int64_t)iA * 192 + g] : 0.f;
          const int iB = idxl[1][tn2];
          dgnB = (iB >= 0) ? delta_gi[(int64_t)iB * 192 + g] : 0.f;
        }
      }
      barrier_lgkm();  // B1
      barrier_lgkm();  // B2
    }
  } else {
    // ---------------- consumer (one of r/z/n for one row) ----------------
    const int row = wave / 3;       // waves 0-2: row 0; waves 3-5: row 1
    const int cw = wave - row * 3;  // 0=r, 1=z, 2=n
    const int j = lane;
    const float* wc = w_hh + (cw * 64 + j) * 64;
    ALL16(DECL_WC)
    const float bc = b_hh[cw * 64 + j];
    float* xrow = x + (b0 + row) * 32768;
    __builtin_amdgcn_s_setprio(1);  // consumers are the critical path
    barrier_lgkm();  // B0
    const float4* hs4 = (const float4*)hs[row];
    float hj = 0.f;
    for (int t = 0; t < 512; ++t) {
      const int bs = t & 1;
      const float gp = gpart[row][bs][0][cw * 64 + j] +
                       gpart[row][bs][1][cw * 64 + j];
      float a0 = bc, a1 = 0.f, a2 = 0.f, a3 = 0.f;
      ALLQ(CCH)
      const float hacc = (a0 + a1) + (a2 + a3);
      if (cw == 0) rbuf[row][j] = fsig_(gp + hacc);
      else if (cw == 1) zbuf[row][j] = fsig_(gp + hacc);
      barrier_lgkm();  // B1: r,z (and gi[t+1]) published
      if (cw == 2) {
        const float r = rbuf[row][j];
        const float z = zbuf[row][j];
        const float n = ftanh_(gp + r * hacc);
        hj = (1.f - z) * n + z * hj;
        hs[row][j] = hj;
        xrow[t * 64 + j] = hj;
      }
      barrier_lgkm();  // B2: h(t) published
    }
  }
}

__global__ __launch_bounds__(64) void graphemb_kernel(
    const float* __restrict__ col_sum, float* __restrict__ graph_emb)
{
  const int h = threadIdx.x;
  float s = 0.f;
#pragma unroll 8
  for (int j = 0; j < 512; ++j) s += col_sum[j * 64 + h];
  graph_emb[h] = s * (1.f / 262144.f);
  if (h < 4) graph_emb[64 + h] = 0.f;
}

// One block per (path, direction). 7-step GRU, D=68, gates 204.
__global__ __launch_bounds__(256) void path_kernel(
    const float* __restrict__ x, const int* __restrict__ paths,
    const float* __restrict__ demands, const float* __restrict__ wd,
    const float* __restrict__ graph_emb,
    const float* __restrict__ wih_f, const float* __restrict__ whh_f,
    const float* __restrict__ bih_f, const float* __restrict__ bhh_f,
    const float* __restrict__ wih_b, const float* __restrict__ whh_b,
    const float* __restrict__ bih_b, const float* __restrict__ bhh_b,
    float* __restrict__ h_out)
{
  const int p = blockIdx.x & 63;
  const int dir = blockIdx.x >> 6;
  const int g = threadIdx.x;
  const float* w_ih = dir ? wih_b : wih_f;
  const float* w_hh = dir ? whh_b : whh_f;
  const float* bih = dir ? bih_b : bih_f;
  const float* bhh = dir ? bhh_b : bhh_f;
  __shared__ float feat[7][68], hs[68], rbuf[68], zbuf[68];
  if (g < 68) {
#pragma unroll
    for (int t = 0; t < 7; ++t) {
      const int src = paths[p * 8 + t];
      const int dst = paths[p * 8 + t + 1];
      feat[t][g] = (g < 64) ? x[((int64_t)src * 512 + dst) * 64 + g]
                            : fmaxf(demands[p] * wd[g - 64], 0.f);
    }
    hs[g] = graph_emb[g];
  }
  __syncthreads();
  for (int s = 0; s < 7; ++s) {
    const int t = dir ? (6 - s) : s;
    float acc = 0.f, hacc = 0.f;
    if (g < 204) {
      acc = bih[g];
      hacc = bhh[g];
      for (int k = 0; k < 68; ++k) {
        acc += feat[t][k] * w_ih[g * 68 + k];
        hacc += hs[k] * w_hh[g * 68 + k];
      }
    }
    if (g < 68) rbuf[g] = sig_(acc + hacc);
    else if (g < 136) zbuf[g - 68] = sig_(acc + hacc);
    __syncthreads();
    if (g >= 136 && g < 204) {
      const int j = g - 136;
      const float n = tanhf(acc + rbuf[j] * hacc);
      const float z = zbuf[j];
      const float hn = (1.f - z) * n + z * hs[j];
      hs[j] = hn;
    }
    __syncthreads();
  }
  if (g < 68) h_out[(dir * 64 + p) * 68 + g] = hs[g];
}

__global__ __launch_bounds__(64) void combine_kernel(
    const float* __restrict__ h_out, const float* __restrict__ wq,
    const float* __restrict__ bq, float* __restrict__ out)
{
  const int p = threadIdx.x;
  float l = bq[0];
#pragma unroll
  for (int d = 0; d < 68; ++d)
    l += 0.5f * (h_out[p * 68 + d] + h_out[(64 + p) * 68 + d]) * wq[d];
  float mx = l;
#pragma unroll
  for (int off = 32; off > 0; off >>= 1) mx = fmaxf(mx, __shfl_xor(mx, off, 64));
  const float e = expf(l - mx);
  float s = e;
#pragma unroll
  for (int off = 32; off > 0; off >>= 1) s += __shfl_xor(s, off, 64);
  out[p] = e / s;
}

extern "C" void kernel_launch(void* const* d_in, const int* in_sizes, int n_in,
                              void* d_out, int out_size, void* d_ws, size_t ws_size,
                              hipStream_t stream)
{
  const float* adj = (const float*)d_in[0];
  const int* edges = (const int*)d_in[1];
  const int* paths = (const int*)d_in[2];
  const float* demands = (const float*)d_in[3];
  const float* emb_w = (const float*)d_in[4];
  const float* w1s = (const float*)d_in[5];
  const float* w2s = (const float*)d_in[6];
  const float* w3s = (const float*)d_in[7];
  const float* gru_w_ih = (const float*)d_in[8];
  const float* gru_w_hh = (const float*)d_in[9];
  const float* gru_b_ih = (const float*)d_in[10];
  const float* gru_b_hh = (const float*)d_in[11];
  const float* pf_w_ih = (const float*)d_in[12];
  const float* pf_w_hh = (const float*)d_in[13];
  const float* pf_b_ih = (const float*)d_in[14];
  const float* pf_b_hh = (const float*)d_in[15];
  const float* pb_w_ih = (const float*)d_in[16];
  const float* pb_w_hh = (const float*)d_in[17];
  const float* pb_b_ih = (const float*)d_in[18];
  const float* pb_b_hh = (const float*)d_in[19];
  const float* wq = (const float*)d_in[20];
  const float* bq = (const float*)d_in[21];
  const float* wd = (const float*)d_in[22];
  float* out = (float*)d_out;

  // Workspace layout (floats): ~74.6 MB total (known-safe size)
  float* xA = (float*)d_ws;                    // 512*512*64 = 16777216
  float* col_sum = xA + 16777216;              // 32768
  int* col_nz = (int*)(col_sum + 32768);       // 512
  int* idxmap = col_nz + 512;                  // 262144
  float* delta_gi = (float*)(idxmap + 262144); // 8192*192 = 1572864
  float* graph_emb = delta_gi + 1572864;       // 68 (+pad)
  float* h_out = graph_emb + 128;              // 2*64*68 = 8704

  hipMemsetAsync(idxmap, 0xFF, 262144 * sizeof(int), stream);
  scatter_idx_kernel<<<32, 256, 0, stream>>>(edges, idxmap);
  embed_kernel<<<65536, 256, 0, stream>>>(adj, emb_w, xA);

  for (int t = 0; t < 3; ++t) {
    colsum_kernel<<<512, 256, 0, stream>>>(xA, col_sum, col_nz);
    edge_kernel<<<8192, 64, 0, stream>>>(xA, edges, col_sum, col_nz,
        w1s + t * 4096, w2s + t * 4096, w3s + t * 4096, gru_w_ih, delta_gi);
    scan_kernel<<<256, 768, 0, stream>>>(xA, delta_gi, idxmap,
        gru_w_ih, gru_w_hh, gru_b_ih, gru_b_hh);
  }

  colsum_kernel<<<512, 256, 0, stream>>>(xA, col_sum, col_nz);
  graphemb_kernel<<<1, 64, 0, stream>>>(col_sum, graph_emb);
  path_kernel<<<128, 256, 0, stream>>>(xA, paths, demands, wd, graph_emb,
      pf_w_ih, pf_w_hh, pf_b_ih, pf_b_hh,
      pb_w_ih, pb_w_hh, pb_b_ih, pb_b_hh, h_out);
  combine_kernel<<<1, 64, 0, stream>>>(h_out, wq, bq, out);
}